// Round 6
// baseline (5164.802 us; speedup 1.0000x reference)
//
#include <hip/hip_runtime.h>
#include <hip/hip_bf16.h>

typedef __hip_bfloat16 bf16;

#define HWp 9216
#define Wd  96
#define Hd  96
#define Bn  8
#define Cn  256

// Load element i of a d_in-derived array; flag==1 -> fp32, flag==0 -> bf16.
__device__ __forceinline__ float ldf(const void* p, size_t i, int flag) {
    return flag ? ((const float*)p)[i] : __bfloat162float(((const bf16*)p)[i]);
}

// ---------------------------------------------------------------------------
// Kernel 0: input dtype probe (first 4096 uint16 of x as bf16).
// bf16 N(0,1): 0 outliers -> flag 0. fp32 buffer: low-mantissa halves read as
// bf16 have uniform exponents -> ~900/4096 outliers -> flag 1.
// ---------------------------------------------------------------------------
__global__ void detect_dtype(const void* x, int* flag) {
    __shared__ int cnt;
    if (threadIdx.x == 0) cnt = 0;
    __syncthreads();
    const bf16* p = (const bf16*)x;
    int local = 0;
    #pragma unroll
    for (int k = 0; k < 16; ++k) {
        float w = __bfloat162float(p[threadIdx.x * 16 + k]);
        if (!(fabsf(w) < 1000.f)) local++;   // catches NaN too
    }
    atomicAdd(&cnt, local);
    __syncthreads();
    if (threadIdx.x == 0) *flag = (cnt > 64) ? 1 : 0;
}

// ---------------------------------------------------------------------------
// Kernel 1 (per image): dwconv3x3 (SAME, zero-pad) + BN + ReLU, both branches.
// One thread per (c, pixel) of one image. Outputs fp32.
// ---------------------------------------------------------------------------
__global__ __launch_bounds__(256) void dwconv_bn_relu2(
    const void* __restrict__ x, size_t xbase,
    const void* __restrict__ ow, const void* __restrict__ obias,
    const void* __restrict__ og, const void* __restrict__ obeta,
    const void* __restrict__ om, const void* __restrict__ ov,
    const void* __restrict__ aw, const void* __restrict__ abias,
    const void* __restrict__ ag, const void* __restrict__ abeta,
    const void* __restrict__ am, const void* __restrict__ av,
    float* __restrict__ t_off, float* __restrict__ t_att,
    const int* __restrict__ flagp)
{
    const int flag = *flagp;
    int idx = blockIdx.x * 256 + threadIdx.x;          // < C*HW
    int hw  = idx % HWp;
    int c   = idx / HWp;                               // [0,256)
    int i   = hw / Wd;
    int j   = hw % Wd;
    size_t base = xbase + (size_t)c * HWp;

    float so = 0.f, sa = 0.f;
    for (int di = -1; di <= 1; ++di) {
        int ii = i + di;
        if (ii < 0 || ii >= Hd) continue;
        for (int dj = -1; dj <= 1; ++dj) {
            int jj = j + dj;
            if (jj < 0 || jj >= Wd) continue;
            float xv = ldf(x, base + ii * Wd + jj, flag);
            int k = (di + 1) * 3 + (dj + 1);
            so += xv * ldf(ow, c * 9 + k, flag);
            sa += xv * ldf(aw, c * 9 + k, flag);
        }
    }
    so += ldf(obias, c, flag);
    sa += ldf(abias, c, flag);
    float sc_o = ldf(og, c, flag) * rsqrtf(ldf(ov, c, flag) + 1e-5f);
    float sc_a = ldf(ag, c, flag) * rsqrtf(ldf(av, c, flag) + 1e-5f);
    float to = (so - ldf(om, c, flag)) * sc_o + ldf(obeta, c, flag);
    float ta = (sa - ldf(am, c, flag)) * sc_a + ldf(abeta, c, flag);
    t_off[idx] = fmaxf(to, 0.f);
    t_att[idx] = fmaxf(ta, 0.f);
}

// ---------------------------------------------------------------------------
// Naive per-image 1x1 conv: out[o,hw] = act(sum_c w[o,c]*in[c,hw] + bias[o])(+res)
// grid = (HW/256, Cout/8); thread handles 1 pixel x 8 outputs. No LDS.
// INF: in is d_in-derived (flag dtype) at element base in_base; else fp32 ws.
// Output is ALWAYS fp32 (d_out is fp32 per reference output dtype).
// ---------------------------------------------------------------------------
template <bool INF, int ACT, bool RES>
__global__ __launch_bounds__(256) void conv1x1_naive(
    const void* __restrict__ in, size_t in_base,
    const void* __restrict__ w, const void* __restrict__ bias,
    const void* __restrict__ res, size_t res_base,
    float* __restrict__ out, const int* __restrict__ flagp)
{
    const int flag = *flagp;
    int hw = blockIdx.x * 256 + threadIdx.x;           // [0, 9216)
    int o0 = blockIdx.y * 8;

    float acc[8] = {};
    for (int c = 0; c < 256; ++c) {
        float xv = INF ? ldf(in, in_base + (size_t)c * HWp + hw, flag)
                       : ((const float*)in)[(size_t)c * HWp + hw];
        #pragma unroll
        for (int i = 0; i < 8; ++i)
            acc[i] += xv * ldf(w, (size_t)(o0 + i) * 256 + c, flag);
    }
    #pragma unroll
    for (int i = 0; i < 8; ++i) {
        int o = o0 + i;
        float v = acc[i] + ldf(bias, o, flag);
        if (ACT == 1) v = 1.f / (1.f + expf(-v));
        if (RES) v += ldf(res, res_base + (size_t)o * HWp + hw, flag);
        out[(size_t)o * HWp + hw] = v;
    }
}

// ---------------------------------------------------------------------------
// Kernel 5 (per image): bilinear sample + attention-weighted sum, 4 points.
// ix = j + 0.5 + 47.5*ox (exact: linspace(0.5,95.5,96) has step exactly 1.0,
// so (ref_x[j]+ox+1)*47.5 = j+0.5+47.5*ox).
// Tap dropped unless coord in [0,95] (grid_sample zeros padding). All fp32.
// ---------------------------------------------------------------------------
__global__ __launch_bounds__(256) void deform_sample(
    const float* __restrict__ value,    // (256, HW), c = n*32+d
    const float* __restrict__ offset,   // (64, HW),  ch = n*8 + 2p + d
    const float* __restrict__ attn,     // (32, HW),  ch = n*4 + p
    float* __restrict__ out_pre)        // (256, HW)
{
    int idx = blockIdx.x * 256 + threadIdx.x;          // < C*HW
    int hw  = idx % HWp;
    int c   = idx / HWp;
    int n   = c >> 5;                   // head (dh = 32)
    int i   = hw / Wd;
    int j   = hw % Wd;

    const float* vp   = value  + (size_t)c * HWp;
    const float* offp = offset + (size_t)(n * 8) * HWp + hw;
    const float* attp = attn   + (size_t)(n * 4) * HWp + hw;

    float acc = 0.f;
    for (int p = 0; p < 4; ++p) {
        float ox = offp[(2 * p) * HWp];
        float oy = offp[(2 * p + 1) * HWp];
        float a  = attp[p * HWp];
        float ix = (float)j + 0.5f + ox * 47.5f;
        float iy = (float)i + 0.5f + oy * 47.5f;
        float x0 = floorf(ix), y0 = floorf(iy);
        float wx1 = ix - x0, wy1 = iy - y0;
        float wx0 = 1.f - wx1, wy0 = 1.f - wy1;
        float xc[2]  = { x0, x0 + 1.f };
        float yc[2]  = { y0, y0 + 1.f };
        float wxs[2] = { wx0, wx1 };
        float wys[2] = { wy0, wy1 };
        float s = 0.f;
        for (int tyi = 0; tyi < 2; ++tyi) {
            if (yc[tyi] < 0.f || yc[tyi] > 95.f) continue;
            int yi = (int)yc[tyi];
            for (int txi = 0; txi < 2; ++txi) {
                if (xc[txi] < 0.f || xc[txi] > 95.f) continue;
                int xi = (int)xc[txi];
                s += wys[tyi] * wxs[txi] * vp[yi * Wd + xi];
            }
        }
        acc += s * a;
    }
    out_pre[idx] = acc;
}

// ---------------------------------------------------------------------------
// Per-image pipeline, all-fp32 workspace, NO aliasing. Peak 39.4 MiB:
//   flag @ 0 (256 B)
//   t_off / t_att / value / out_pre  f32, 9.44 MB each
//   offset f32 (2.36 MB), attn f32 (1.18 MB)
// d_out (fp32!) written ONLY by the final kernel.
// ---------------------------------------------------------------------------
extern "C" void kernel_launch(void* const* d_in, const int* in_sizes, int n_in,
                              void* d_out, int out_size, void* d_ws, size_t ws_size,
                              hipStream_t stream)
{
    const void* x        = d_in[0];
    const void* off_dw_w = d_in[1];
    const void* off_dw_b = d_in[2];
    const void* off_bn_g = d_in[3];
    const void* off_bn_b = d_in[4];
    const void* off_bn_m = d_in[5];
    const void* off_bn_v = d_in[6];
    const void* off_pw_w = d_in[7];
    const void* off_pw_b = d_in[8];
    const void* att_dw_w = d_in[9];
    const void* att_dw_b = d_in[10];
    const void* att_bn_g = d_in[11];
    const void* att_bn_b = d_in[12];
    const void* att_bn_m = d_in[13];
    const void* att_bn_v = d_in[14];
    const void* att_pw_w = d_in[15];
    const void* att_pw_b = d_in[16];
    const void* val_w    = d_in[17];
    const void* val_b    = d_in[18];
    const void* out_w    = d_in[19];
    const void* out_b    = d_in[20];

    const size_t IMG = (size_t)Cn * HWp;               // 2,359,296 elem/image
    const size_t F   = IMG * sizeof(float);            // 9,437,184 B

    char* ws = (char*)d_ws;
    int*   flag    = (int*)ws;
    float* t_off   = (float*)(ws + 256);
    float* t_att   = (float*)(ws + 256 + F);
    float* value   = (float*)(ws + 256 + 2 * F);
    float* out_pre = (float*)(ws + 256 + 3 * F);
    float* offset  = (float*)(ws + 256 + 4 * F);
    float* attnb   = (float*)(ws + 256 + 4 * F + (size_t)64 * HWp * 4);

    const int nBlk = (int)(IMG / 256);                 // 9216
    const dim3 gOff(HWp / 256, 64 / 8);                // (36, 8)
    const dim3 gAtt(HWp / 256, 32 / 8);                // (36, 4)
    const dim3 gBig(HWp / 256, 256 / 8);               // (36, 32)

    detect_dtype<<<1, 256, 0, stream>>>(x, flag);

    for (int b = 0; b < Bn; ++b) {
        size_t xelem = (size_t)b * IMG;
        float* outp  = (float*)d_out + xelem;          // fp32 output!

        // 1. dwconv + BN + ReLU (both branches)
        dwconv_bn_relu2<<<nBlk, 256, 0, stream>>>(
            x, xelem, off_dw_w, off_dw_b, off_bn_g, off_bn_b, off_bn_m, off_bn_v,
            att_dw_w, att_dw_b, att_bn_g, att_bn_b, att_bn_m, att_bn_v,
            t_off, t_att, flag);

        // 2. offset = t_off @ off_pw_w^T  (64 ch)
        conv1x1_naive<false, 0, false><<<gOff, 256, 0, stream>>>(
            t_off, 0, off_pw_w, off_pw_b, nullptr, 0, offset, flag);

        // 3. attn = sigmoid(t_att @ att_pw_w^T)  (32 ch)
        conv1x1_naive<false, 1, false><<<gAtt, 256, 0, stream>>>(
            t_att, 0, att_pw_w, att_pw_b, nullptr, 0, attnb, flag);

        // 4. value = x @ val_w^T  (256 ch)
        conv1x1_naive<true, 0, false><<<gBig, 256, 0, stream>>>(
            x, xelem, val_w, val_b, nullptr, 0, value, flag);

        // 5. deformable bilinear sampling + attention sum
        deform_sample<<<nBlk, 256, 0, stream>>>(value, offset, attnb, out_pre);

        // 6. final projection + bias + residual -> d_out (FP32)
        conv1x1_naive<false, 0, true><<<gBig, 256, 0, stream>>>(
            out_pre, 0, out_w, out_b, x, xelem, outp, flag);
    }
}

// Round 7
// 1234.664 us; speedup vs baseline: 4.1832x; 4.1832x over previous
//
#include <hip/hip_runtime.h>
#include <hip/hip_bf16.h>

typedef __hip_bfloat16 bf16;

#define HWp 9216
#define Wd  96
#define Hd  96
#define Bn  8
#define Cn  256
#define IMG ((size_t)Cn * HWp)          // 2,359,296 elements per image

// Load element i of a d_in-derived array; flag==1 -> fp32, flag==0 -> bf16.
__device__ __forceinline__ float ldf(const void* p, size_t i, int flag) {
    return flag ? ((const float*)p)[i] : __bfloat162float(((const bf16*)p)[i]);
}

// ---------------------------------------------------------------------------
// Kernel 0: input dtype probe (fp32 expected; bf16 fallback kept as insurance)
// ---------------------------------------------------------------------------
__global__ void detect_dtype(const void* x, int* flag) {
    __shared__ int cnt;
    if (threadIdx.x == 0) cnt = 0;
    __syncthreads();
    const bf16* p = (const bf16*)x;
    int local = 0;
    #pragma unroll
    for (int k = 0; k < 16; ++k) {
        float w = __bfloat162float(p[threadIdx.x * 16 + k]);
        if (!(fabsf(w) < 1000.f)) local++;   // catches NaN too
    }
    atomicAdd(&cnt, local);
    __syncthreads();
    if (threadIdx.x == 0) *flag = (cnt > 64) ? 1 : 0;
}

// ---------------------------------------------------------------------------
// Kernel 1 (per chunk of images): dwconv3x3 (SAME, zero-pad) + BN + ReLU,
// both branches. One thread per (img, c, pixel). Outputs fp32 into chunk ws.
// ---------------------------------------------------------------------------
__global__ __launch_bounds__(256) void dwconv_bn_relu2(
    const void* __restrict__ x, size_t xbase,      // element base of chunk
    const void* __restrict__ ow, const void* __restrict__ obias,
    const void* __restrict__ og, const void* __restrict__ obeta,
    const void* __restrict__ om, const void* __restrict__ ov,
    const void* __restrict__ aw, const void* __restrict__ abias,
    const void* __restrict__ ag, const void* __restrict__ abeta,
    const void* __restrict__ am, const void* __restrict__ av,
    float* __restrict__ t_off, float* __restrict__ t_att,
    const int* __restrict__ flagp)
{
    const int flag = *flagp;
    int idx = blockIdx.x * 256 + threadIdx.x;      // < k*C*HW
    int hw  = idx % HWp;
    int bc  = idx / HWp;                           // img*256 + c
    int c   = bc & 255;
    int i   = hw / Wd;
    int j   = hw % Wd;
    size_t base = xbase + (size_t)bc * HWp;

    float so = 0.f, sa = 0.f;
    #pragma unroll
    for (int di = -1; di <= 1; ++di) {
        int ii = i + di;
        if (ii < 0 || ii >= Hd) continue;
        #pragma unroll
        for (int dj = -1; dj <= 1; ++dj) {
            int jj = j + dj;
            if (jj < 0 || jj >= Wd) continue;
            float xv = ldf(x, base + ii * Wd + jj, flag);
            int k = (di + 1) * 3 + (dj + 1);
            so += xv * ldf(ow, c * 9 + k, flag);
            sa += xv * ldf(aw, c * 9 + k, flag);
        }
    }
    so += ldf(obias, c, flag);
    sa += ldf(abias, c, flag);
    float sc_o = ldf(og, c, flag) * rsqrtf(ldf(ov, c, flag) + 1e-5f);
    float sc_a = ldf(ag, c, flag) * rsqrtf(ldf(av, c, flag) + 1e-5f);
    float to = (so - ldf(om, c, flag)) * sc_o + ldf(obeta, c, flag);
    float ta = (sa - ldf(am, c, flag)) * sc_a + ldf(abeta, c, flag);
    t_off[idx] = fmaxf(to, 0.f);
    t_att[idx] = fmaxf(ta, 0.f);
}

// ---------------------------------------------------------------------------
// Tiled 1x1-conv GEMM (per chunk): out[img,o,hw] = act(sum_c w[o,c]*in[img,c,hw]
// + bias[o]) (+res). Cin=256. Tile 64 out x 64 px, 256 thr (16x16), 4x4 micro.
// grid = (144*k, ceil(Cout/64)).
// INF: in is d_in-derived (flag dtype) at element base in_base; else fp32 ws
//      (chunk-local, img-major).
// Out always fp32 (ws or d_out). w/bias/res always d_in-derived.
// ---------------------------------------------------------------------------
template <bool INF, int ACT, bool RES>
__global__ __launch_bounds__(256) void conv1x1_tiled(
    const void* __restrict__ in, size_t in_base,
    const void* __restrict__ w, const void* __restrict__ bias,
    const void* __restrict__ res, size_t res_base,
    float* __restrict__ out, int Cout, const int* __restrict__ flagp)
{
    const int flag = *flagp;
    __shared__ float sIn[32][64];      // b128-aligned reads (rows 256 B)
    __shared__ float sW[32][65];       // +1 pad: transposed store conflict-free

    int tid = threadIdx.x;
    int img = blockIdx.x / 144;
    int hw0 = (blockIdx.x % 144) * 64;
    int o0  = blockIdx.y * 64;
    int tx  = tid & 15;                // pixel group
    int ty  = tid >> 4;                // output group

    size_t inImg = (size_t)img * IMG;  // 256-ch input image stride
    float acc[4][4] = {};

    for (int c0 = 0; c0 < 256; c0 += 32) {
        // stage input tile 32 ch x 64 px
        if (!INF || flag) {            // fp32 source -> float4 staging
            const float* src = (const float*)in + (INF ? in_base : 0) + inImg;
            #pragma unroll
            for (int it = 0; it < 2; ++it) {
                int ix  = it * 256 + tid;          // float4 index
                int cc  = ix >> 4;
                int px4 = (ix & 15) * 4;
                float4 v = *(const float4*)(src + (size_t)(c0 + cc) * HWp + hw0 + px4);
                *(float4*)&sIn[cc][px4] = v;
            }
        } else {                       // bf16 source -> scalar staging
            const bf16* src = (const bf16*)in + in_base + inImg;
            #pragma unroll
            for (int it = 0; it < 8; ++it) {
                int ix = it * 256 + tid;
                int cc = ix >> 6, px = ix & 63;
                sIn[cc][px] = __bfloat162float(src[(size_t)(c0 + cc) * HWp + hw0 + px]);
            }
        }
        // stage weight tile 64 out x 32 ch (transposed)
        #pragma unroll
        for (int it = 0; it < 8; ++it) {
            int ix = it * 256 + tid;
            int oo = ix >> 5, cc = ix & 31;
            int o  = o0 + oo;
            sW[cc][oo] = (o < Cout) ? ldf(w, (size_t)o * 256 + c0 + cc, flag) : 0.f;
        }
        __syncthreads();
        #pragma unroll
        for (int cc = 0; cc < 32; ++cc) {
            float4 xi = *(const float4*)&sIn[cc][tx * 4];
            float wi[4];
            #pragma unroll
            for (int i = 0; i < 4; ++i) wi[i] = sW[cc][ty * 4 + i];
            #pragma unroll
            for (int i = 0; i < 4; ++i) {
                acc[i][0] += wi[i] * xi.x;
                acc[i][1] += wi[i] * xi.y;
                acc[i][2] += wi[i] * xi.z;
                acc[i][3] += wi[i] * xi.w;
            }
        }
        __syncthreads();
    }

    size_t outImg = (size_t)img * ((size_t)Cout * HWp);
    size_t resImg = res_base + inImg;      // residual has 256 ch (Cout==256)
    #pragma unroll
    for (int i = 0; i < 4; ++i) {
        int o = o0 + ty * 4 + i;
        if (o >= Cout) continue;
        float bv = ldf(bias, o, flag);
        float4 v;
        float* vv = (float*)&v;
        #pragma unroll
        for (int j = 0; j < 4; ++j) {
            float t = acc[i][j] + bv;
            if (ACT == 1) t = 1.f / (1.f + __expf(-t));
            if (RES) t += ldf(res, resImg + (size_t)o * HWp + hw0 + tx * 4 + j, flag);
            vv[j] = t;
        }
        *(float4*)(out + outImg + (size_t)o * HWp + hw0 + tx * 4) = v;
    }
}

// ---------------------------------------------------------------------------
// Kernel 5 (per chunk): bilinear sample + attention-weighted sum, 4 points.
// ix = j + 0.5 + 47.5*ox (exact). Tap dropped unless coord in [0,95].
// Lanes = consecutive pixels of one channel -> gathers coalesce when offsets
// are smooth. All fp32, chunk-local buffers.
// ---------------------------------------------------------------------------
__global__ __launch_bounds__(256) void deform_sample(
    const float* __restrict__ value,    // (k,256,HW), c = n*32+d
    const float* __restrict__ offset,   // (k,64,HW),  ch = n*8 + 2p + d
    const float* __restrict__ attn,     // (k,32,HW),  ch = n*4 + p
    float* __restrict__ out_pre)        // (k,256,HW)
{
    int idx = blockIdx.x * 256 + threadIdx.x;
    int hw  = idx % HWp;
    int bc  = idx / HWp;
    int c   = bc & 255;
    int img = bc >> 8;
    int n   = c >> 5;                   // head (dh = 32)
    int i   = hw / Wd;
    int j   = hw % Wd;

    const float* vp   = value  + (size_t)bc * HWp;
    const float* offp = offset + ((size_t)img * 64 + n * 8) * HWp + hw;
    const float* attp = attn   + ((size_t)img * 32 + n * 4) * HWp + hw;

    float acc = 0.f;
    #pragma unroll
    for (int p = 0; p < 4; ++p) {
        float ox = offp[(2 * p) * HWp];
        float oy = offp[(2 * p + 1) * HWp];
        float a  = attp[p * HWp];
        float ix = (float)j + 0.5f + ox * 47.5f;
        float iy = (float)i + 0.5f + oy * 47.5f;
        float x0 = floorf(ix), y0 = floorf(iy);
        float wx1 = ix - x0, wy1 = iy - y0;
        float wx0 = 1.f - wx1, wy0 = 1.f - wy1;
        float xc[2]  = { x0, x0 + 1.f };
        float yc[2]  = { y0, y0 + 1.f };
        float wxs[2] = { wx0, wx1 };
        float wys[2] = { wy0, wy1 };
        float s = 0.f;
        #pragma unroll
        for (int tyi = 0; tyi < 2; ++tyi) {
            if (yc[tyi] < 0.f || yc[tyi] > 95.f) continue;
            int yi = (int)yc[tyi];
            #pragma unroll
            for (int txi = 0; txi < 2; ++txi) {
                if (xc[txi] < 0.f || xc[txi] > 95.f) continue;
                int xi = (int)xc[txi];
                s += wys[tyi] * wxs[txi] * vp[yi * Wd + xi];
            }
        }
        acc += s * a;
    }
    out_pre[idx] = acc;
}

// ---------------------------------------------------------------------------
// Chunked pipeline. Per-image ws need: (2*IMG + 96*HWp)*4 = 22,413,312 B.
// Chunk size k = largest of {8,4,2,1} fitting ws_size (k=1 needs 21.4 MiB,
// <= 39.4 MiB proven safe in R6). Layout per chunk (fp32):
//   flag @0 (256 B)
//   A @256:      t_off (k1..k2) -> out_pre (k5..k6)      k*IMG
//   B @+k*IMG:   t_att (k1..k3) -> value   (k4..k5)      k*IMG
//   C @+k*IMG:   offset (k2..k5)                          k*64*HWp
//   D @+k*64HW:  attn   (k3..k5)                          k*32*HWp
// d_out (fp32) written ONLY by the final kernel.
// ---------------------------------------------------------------------------
extern "C" void kernel_launch(void* const* d_in, const int* in_sizes, int n_in,
                              void* d_out, int out_size, void* d_ws, size_t ws_size,
                              hipStream_t stream)
{
    const void* x        = d_in[0];
    const void* off_dw_w = d_in[1];
    const void* off_dw_b = d_in[2];
    const void* off_bn_g = d_in[3];
    const void* off_bn_b = d_in[4];
    const void* off_bn_m = d_in[5];
    const void* off_bn_v = d_in[6];
    const void* off_pw_w = d_in[7];
    const void* off_pw_b = d_in[8];
    const void* att_dw_w = d_in[9];
    const void* att_dw_b = d_in[10];
    const void* att_bn_g = d_in[11];
    const void* att_bn_b = d_in[12];
    const void* att_bn_m = d_in[13];
    const void* att_bn_v = d_in[14];
    const void* att_pw_w = d_in[15];
    const void* att_pw_b = d_in[16];
    const void* val_w    = d_in[17];
    const void* val_b    = d_in[18];
    const void* out_w    = d_in[19];
    const void* out_b    = d_in[20];

    const size_t perImg = (2 * IMG + (size_t)96 * HWp) * sizeof(float);
    int k = 1;
    if      (ws_size >= 256 + 8 * perImg) k = 8;
    else if (ws_size >= 256 + 4 * perImg) k = 4;
    else if (ws_size >= 256 + 2 * perImg) k = 2;

    char* ws = (char*)d_ws;
    int*   flag    = (int*)ws;
    float* A       = (float*)(ws + 256);                  // t_off / out_pre
    float* Bp      = A + (size_t)k * IMG;                 // t_att / value
    float* offset  = Bp + (size_t)k * IMG;
    float* attnb   = offset + (size_t)k * 64 * HWp;

    detect_dtype<<<1, 256, 0, stream>>>(x, flag);

    const int nBlk = k * (int)(IMG / 256);                // k*9216
    const dim3 gS(144 * k, 1);                            // Cout<=64
    const dim3 gB(144 * k, 4);                            // Cout=256

    for (int b0 = 0; b0 < Bn; b0 += k) {
        size_t xelem = (size_t)b0 * IMG;
        float* outp  = (float*)d_out + xelem;

        // 1. dwconv + BN + ReLU (both branches) -> A, B
        dwconv_bn_relu2<<<nBlk, 256, 0, stream>>>(
            x, xelem, off_dw_w, off_dw_b, off_bn_g, off_bn_b, off_bn_m, off_bn_v,
            att_dw_w, att_dw_b, att_bn_g, att_bn_b, att_bn_m, att_bn_v,
            A, Bp, flag);

        // 2. offset = t_off @ off_pw_w^T (64 ch) -> C
        conv1x1_tiled<false, 0, false><<<gS, 256, 0, stream>>>(
            A, 0, off_pw_w, off_pw_b, nullptr, 0, offset, 64, flag);

        // 3. attn = sigmoid(t_att @ att_pw_w^T) (32 ch) -> D
        conv1x1_tiled<false, 1, false><<<gS, 256, 0, stream>>>(
            Bp, 0, att_pw_w, att_pw_b, nullptr, 0, attnb, 32, flag);

        // 4. value = x @ val_w^T (256 ch) -> B (t_att dead)
        conv1x1_tiled<true, 0, false><<<gB, 256, 0, stream>>>(
            x, xelem, val_w, val_b, nullptr, 0, Bp, 256, flag);

        // 5. deformable sampling + attention sum -> A (t_off dead)
        deform_sample<<<nBlk, 256, 0, stream>>>(Bp, offset, attnb, A);

        // 6. final projection + bias + residual -> d_out (fp32)
        conv1x1_tiled<false, 0, true><<<gB, 256, 0, stream>>>(
            A, 0, out_w, out_b, x, xelem, outp, 256, flag);
    }
}

// Round 8
// 1100.761 us; speedup vs baseline: 4.6920x; 1.1216x over previous
//
#include <hip/hip_runtime.h>
#include <hip/hip_bf16.h>

typedef __hip_bfloat16 bf16;

#define HWp 9216
#define Wd  96
#define Hd  96
#define Bn  8
#define Cn  256
#define IMG ((size_t)Cn * HWp)          // 2,359,296 elements per image

// Load element i of a d_in-derived array; flag==1 -> fp32, flag==0 -> bf16.
__device__ __forceinline__ float ldf(const void* p, size_t i, int flag) {
    return flag ? ((const float*)p)[i] : __bfloat162float(((const bf16*)p)[i]);
}

// ---------------------------------------------------------------------------
// Kernel 0: input dtype probe (fp32 expected; bf16 fallback kept as insurance)
// ---------------------------------------------------------------------------
__global__ void detect_dtype(const void* x, int* flag) {
    __shared__ int cnt;
    if (threadIdx.x == 0) cnt = 0;
    __syncthreads();
    const bf16* p = (const bf16*)x;
    int local = 0;
    #pragma unroll
    for (int k = 0; k < 16; ++k) {
        float w = __bfloat162float(p[threadIdx.x * 16 + k]);
        if (!(fabsf(w) < 1000.f)) local++;
    }
    atomicAdd(&cnt, local);
    __syncthreads();
    if (threadIdx.x == 0) *flag = (cnt > 64) ? 1 : 0;
}

// ---------------------------------------------------------------------------
// Kernel 1: dwconv3x3 (SAME, zero-pad) + BN + ReLU, both branches. CHW out.
// ---------------------------------------------------------------------------
__global__ __launch_bounds__(256) void dwconv_bn_relu2(
    const void* __restrict__ x, size_t xbase,
    const void* __restrict__ ow, const void* __restrict__ obias,
    const void* __restrict__ og, const void* __restrict__ obeta,
    const void* __restrict__ om, const void* __restrict__ ov,
    const void* __restrict__ aw, const void* __restrict__ abias,
    const void* __restrict__ ag, const void* __restrict__ abeta,
    const void* __restrict__ am, const void* __restrict__ av,
    float* __restrict__ t_off, float* __restrict__ t_att,
    const int* __restrict__ flagp)
{
    const int flag = *flagp;
    int idx = blockIdx.x * 256 + threadIdx.x;
    int hw  = idx % HWp;
    int bc  = idx / HWp;
    int c   = bc & 255;
    int i   = hw / Wd;
    int j   = hw % Wd;
    size_t base = xbase + (size_t)bc * HWp;

    float so = 0.f, sa = 0.f;
    #pragma unroll
    for (int di = -1; di <= 1; ++di) {
        int ii = i + di;
        if (ii < 0 || ii >= Hd) continue;
        #pragma unroll
        for (int dj = -1; dj <= 1; ++dj) {
            int jj = j + dj;
            if (jj < 0 || jj >= Wd) continue;
            float xv = ldf(x, base + ii * Wd + jj, flag);
            int k = (di + 1) * 3 + (dj + 1);
            so += xv * ldf(ow, c * 9 + k, flag);
            sa += xv * ldf(aw, c * 9 + k, flag);
        }
    }
    so += ldf(obias, c, flag);
    sa += ldf(abias, c, flag);
    float sc_o = ldf(og, c, flag) * rsqrtf(ldf(ov, c, flag) + 1e-5f);
    float sc_a = ldf(ag, c, flag) * rsqrtf(ldf(av, c, flag) + 1e-5f);
    float to = (so - ldf(om, c, flag)) * sc_o + ldf(obeta, c, flag);
    float ta = (sa - ldf(am, c, flag)) * sc_a + ldf(abeta, c, flag);
    t_off[idx] = fmaxf(to, 0.f);
    t_att[idx] = fmaxf(ta, 0.f);
}

// ---------------------------------------------------------------------------
// Tiled 1x1-conv GEMM. Tile 64 out x 64 px, 256 thr (16x16), 4x4 microtile.
// INMODE: 0 = fp32 ws, CHW (img,c,hw)
//         1 = d_in (flag dtype), CHW
//         2 = fp32 ws, HWC (img,hw,c)
// OUTHWC: true -> out[img, hw, o] (fp32 ws), false -> out[img, o, hw]
// ACT: 0 none, 1 sigmoid. RES: add residual (d_in CHW, Cout==256 only).
// ---------------------------------------------------------------------------
template <int INMODE, bool OUTHWC, int ACT, bool RES>
__global__ __launch_bounds__(256) void conv1x1_tiled(
    const void* __restrict__ in, size_t in_base,
    const void* __restrict__ w, const void* __restrict__ bias,
    const void* __restrict__ res, size_t res_base,
    float* __restrict__ out, int Cout, const int* __restrict__ flagp)
{
    const int flag = *flagp;
    __shared__ float sIn[32][64];
    __shared__ float sW[32][65];       // +1 pad: transposed store conflict-free

    int tid = threadIdx.x;
    int img = blockIdx.x / 144;
    int hw0 = (blockIdx.x % 144) * 64;
    int o0  = blockIdx.y * 64;
    int tx  = tid & 15;                // pixel group
    int ty  = tid >> 4;                // output group

    float acc[4][4] = {};

    for (int c0 = 0; c0 < 256; c0 += 32) {
        // ---- stage input tile: 32 ch x 64 px -> sIn[cc][px]
        if (INMODE == 2) {
            // HWC ws: wave-uniform c-quad, px = lane -> conflict-free stores
            const float* src = (const float*)in + (size_t)img * IMG;
            #pragma unroll
            for (int it = 0; it < 2; ++it) {
                int q  = it * 4 + (tid >> 6);       // 0..7, wave-uniform
                int px = tid & 63;
                float4 v = *(const float4*)(src + (size_t)(hw0 + px) * 256 + c0 + q * 4);
                sIn[q * 4 + 0][px] = v.x;
                sIn[q * 4 + 1][px] = v.y;
                sIn[q * 4 + 2][px] = v.z;
                sIn[q * 4 + 3][px] = v.w;
            }
        } else if (INMODE == 0 || flag) {
            const float* src = (const float*)in + (INMODE == 1 ? in_base : 0)
                             + (size_t)img * IMG;
            #pragma unroll
            for (int it = 0; it < 2; ++it) {
                int ix  = it * 256 + tid;
                int cc  = ix >> 4;
                int px4 = (ix & 15) * 4;
                float4 v = *(const float4*)(src + (size_t)(c0 + cc) * HWp + hw0 + px4);
                *(float4*)&sIn[cc][px4] = v;
            }
        } else {                        // bf16 d_in fallback
            const bf16* src = (const bf16*)in + in_base + (size_t)img * IMG;
            #pragma unroll
            for (int it = 0; it < 8; ++it) {
                int ix = it * 256 + tid;
                int cc = ix >> 6, px = ix & 63;
                sIn[cc][px] = __bfloat162float(src[(size_t)(c0 + cc) * HWp + hw0 + px]);
            }
        }
        // ---- stage weight tile 64 out x 32 ch (transposed)
        #pragma unroll
        for (int it = 0; it < 8; ++it) {
            int ix = it * 256 + tid;
            int oo = ix >> 5, cc = ix & 31;
            int o  = o0 + oo;
            sW[cc][oo] = (o < Cout) ? ldf(w, (size_t)o * 256 + c0 + cc, flag) : 0.f;
        }
        __syncthreads();
        #pragma unroll
        for (int cc = 0; cc < 32; ++cc) {
            float4 xi = *(const float4*)&sIn[cc][tx * 4];
            float wi[4];
            #pragma unroll
            for (int i = 0; i < 4; ++i) wi[i] = sW[cc][ty * 4 + i];
            #pragma unroll
            for (int i = 0; i < 4; ++i) {
                acc[i][0] += wi[i] * xi.x;
                acc[i][1] += wi[i] * xi.y;
                acc[i][2] += wi[i] * xi.z;
                acc[i][3] += wi[i] * xi.w;
            }
        }
        __syncthreads();
    }

    if (OUTHWC) {
        size_t outImg = (size_t)img * ((size_t)Cout * HWp);
        #pragma unroll
        for (int j = 0; j < 4; ++j) {
            int hw = hw0 + tx * 4 + j;
            int o  = o0 + ty * 4;
            if (o >= Cout) continue;
            float4 v;
            float* vv = (float*)&v;
            #pragma unroll
            for (int i = 0; i < 4; ++i) {
                float t = acc[i][j] + ldf(bias, o + i, flag);
                if (ACT == 1) t = 1.f / (1.f + __expf(-t));
                vv[i] = t;
            }
            *(float4*)(out + outImg + (size_t)hw * Cout + o) = v;
        }
    } else {
        size_t outImg = (size_t)img * ((size_t)Cout * HWp);
        size_t resImg = res_base + (size_t)img * IMG;
        #pragma unroll
        for (int i = 0; i < 4; ++i) {
            int o = o0 + ty * 4 + i;
            if (o >= Cout) continue;
            float bv = ldf(bias, o, flag);
            float4 v;
            float* vv = (float*)&v;
            #pragma unroll
            for (int j = 0; j < 4; ++j) {
                float t = acc[i][j] + bv;
                if (ACT == 1) t = 1.f / (1.f + __expf(-t));
                if (RES) t += ldf(res, resImg + (size_t)o * HWp + hw0 + tx * 4 + j, flag);
                vv[j] = t;
            }
            *(float4*)(out + outImg + (size_t)o * HWp + hw0 + tx * 4) = v;
        }
    }
}

// ---------------------------------------------------------------------------
// Kernel 5: deformable bilinear sampling + attention sum, channel-last.
// Block = 16 pixels x 256 channels. Phase 1: 512 (pixel,head,point) tasks
// compute 4 tap indices (clamped) + 4 weights (attn & validity folded in),
// stored in LDS. Phase 2: thread = channel; 16 loads+FMA per pixel, taps
// contiguous in C (128B per head) -> full line utilization.
// value HWC (img,hw,c); offset HWC (img,hw,64); attn HWC (img,hw,32);
// out_pre HWC (img,hw,256).
// ---------------------------------------------------------------------------
__global__ __launch_bounds__(256) void deform_sample_hwc(
    const float* __restrict__ value,
    const float* __restrict__ offset,
    const float* __restrict__ attn,
    float* __restrict__ out_pre)
{
    __shared__ int   sIdx[16 * 32 * 4];   // [pix][n*4+p][tap]
    __shared__ float sWt [16 * 32 * 4];

    int tid   = threadIdx.x;
    int pix0  = blockIdx.x * 16;          // global pixel base (chunk-local)

    // ---- phase 1: tap precompute --------------------------------------
    #pragma unroll
    for (int it = 0; it < 2; ++it) {
        int task = it * 256 + tid;        // 512 tasks
        int pix  = task >> 5;             // 0..15
        int np   = task & 31;             // n*4+p
        int gpix = pix0 + pix;
        int hw   = gpix % HWp;
        int i    = hw / Wd;
        int j    = hw % Wd;
        float ox = offset[(size_t)gpix * 64 + np * 2];
        float oy = offset[(size_t)gpix * 64 + np * 2 + 1];
        float a  = attn[(size_t)gpix * 32 + np];
        float ix = (float)j + 0.5f + ox * 47.5f;
        float iy = (float)i + 0.5f + oy * 47.5f;
        float x0 = floorf(ix), y0 = floorf(iy);
        float wx1 = ix - x0, wy1 = iy - y0;
        float wx0 = 1.f - wx1, wy0 = 1.f - wy1;
        int base = task * 4;
        #pragma unroll
        for (int t = 0; t < 4; ++t) {
            float xc = (t & 1) ? x0 + 1.f : x0;
            float yc = (t & 2) ? y0 + 1.f : y0;
            float wt = ((t & 1) ? wx1 : wx0) * ((t & 2) ? wy1 : wy0);
            bool ok  = (xc >= 0.f) & (xc <= 95.f) & (yc >= 0.f) & (yc <= 95.f);
            int xi = min(max((int)xc, 0), 95);
            int yi = min(max((int)yc, 0), 95);
            sIdx[base + t] = yi * Wd + xi;
            sWt [base + t] = ok ? a * wt : 0.f;
        }
    }
    __syncthreads();

    // ---- phase 2: gather + accumulate ---------------------------------
    int c   = tid;                        // 0..255
    int n   = c >> 5;                     // head
    int img = pix0 / HWp;                 // tiles never cross image (9216%16==0)
    const float* vimg = value + (size_t)img * IMG - (size_t)img * HWp * 0; // HWC base
    const float* vbase = value + (size_t)img * HWp * 256;
    int hwImgBase = img * HWp;            // value indexed by local hw

    #pragma unroll 4
    for (int pix = 0; pix < 16; ++pix) {
        int base = (pix * 32 + n * 4) * 4;
        float acc = 0.f;
        #pragma unroll
        for (int p = 0; p < 4; ++p) {
            float4 w4 = *(const float4*)&sWt [base + p * 4];
            int4   i4 = *(const int4*)  &sIdx[base + p * 4];
            acc += w4.x * vbase[(size_t)i4.x * 256 + c];
            acc += w4.y * vbase[(size_t)i4.y * 256 + c];
            acc += w4.z * vbase[(size_t)i4.z * 256 + c];
            acc += w4.w * vbase[(size_t)i4.w * 256 + c];
        }
        out_pre[(size_t)(pix0 + pix) * 256 + c] = acc;
    }
}

// ---------------------------------------------------------------------------
// Chunked pipeline (fp32 ws). Per-image: (2*IMG + 96*HWp)*4 = 22.4 MB.
// Layout per chunk:
//   flag @0 (256 B)
//   A @256:      t_off CHW (k1..k2) -> out_pre HWC (k5..k6)   k*IMG
//   B @+k*IMG:   t_att CHW (k1..k3) -> value  HWC (k4..k5)    k*IMG
//   C @+k*IMG:   offset HWC (k2..k5)                           k*64*HWp
//   D @+k*64HW:  attn   HWC (k3..k5)                           k*32*HWp
// d_out (fp32, CHW) written ONLY by the final kernel.
// ---------------------------------------------------------------------------
extern "C" void kernel_launch(void* const* d_in, const int* in_sizes, int n_in,
                              void* d_out, int out_size, void* d_ws, size_t ws_size,
                              hipStream_t stream)
{
    const void* x        = d_in[0];
    const void* off_dw_w = d_in[1];
    const void* off_dw_b = d_in[2];
    const void* off_bn_g = d_in[3];
    const void* off_bn_b = d_in[4];
    const void* off_bn_m = d_in[5];
    const void* off_bn_v = d_in[6];
    const void* off_pw_w = d_in[7];
    const void* off_pw_b = d_in[8];
    const void* att_dw_w = d_in[9];
    const void* att_dw_b = d_in[10];
    const void* att_bn_g = d_in[11];
    const void* att_bn_b = d_in[12];
    const void* att_bn_m = d_in[13];
    const void* att_bn_v = d_in[14];
    const void* att_pw_w = d_in[15];
    const void* att_pw_b = d_in[16];
    const void* val_w    = d_in[17];
    const void* val_b    = d_in[18];
    const void* out_w    = d_in[19];
    const void* out_b    = d_in[20];

    const size_t perImg = (2 * IMG + (size_t)96 * HWp) * sizeof(float);
    int k = 1;
    if      (ws_size >= 256 + 8 * perImg) k = 8;
    else if (ws_size >= 256 + 4 * perImg) k = 4;
    else if (ws_size >= 256 + 2 * perImg) k = 2;

    char* ws = (char*)d_ws;
    int*   flag    = (int*)ws;
    float* A       = (float*)(ws + 256);                  // t_off / out_pre
    float* Bp      = A + (size_t)k * IMG;                 // t_att / value
    float* offset  = Bp + (size_t)k * IMG;
    float* attnb   = offset + (size_t)k * 64 * HWp;

    detect_dtype<<<1, 256, 0, stream>>>(x, flag);

    const int nBlk  = k * (int)(IMG / 256);               // dwconv blocks
    const int nDef  = k * (HWp / 16);                     // deform blocks
    const dim3 gS(144 * k, 1);                            // Cout<=64
    const dim3 gB(144 * k, 4);                            // Cout=256

    for (int b0 = 0; b0 < Bn; b0 += k) {
        size_t xelem = (size_t)b0 * IMG;
        float* outp  = (float*)d_out + xelem;

        // 1. dwconv + BN + ReLU (both branches) -> A, B (CHW)
        dwconv_bn_relu2<<<nBlk, 256, 0, stream>>>(
            x, xelem, off_dw_w, off_dw_b, off_bn_g, off_bn_b, off_bn_m, off_bn_v,
            att_dw_w, att_dw_b, att_bn_g, att_bn_b, att_bn_m, att_bn_v,
            A, Bp, flag);

        // 2. offset = t_off @ off_pw_w^T (64 ch) -> C (HWC)
        conv1x1_tiled<0, true, 0, false><<<gS, 256, 0, stream>>>(
            A, 0, off_pw_w, off_pw_b, nullptr, 0, offset, 64, flag);

        // 3. attn = sigmoid(t_att @ att_pw_w^T) (32 ch) -> D (HWC)
        conv1x1_tiled<0, true, 1, false><<<gS, 256, 0, stream>>>(
            Bp, 0, att_pw_w, att_pw_b, nullptr, 0, attnb, 32, flag);

        // 4. value = x @ val_w^T (256 ch) -> B (HWC; t_att dead)
        conv1x1_tiled<1, true, 0, false><<<gB, 256, 0, stream>>>(
            x, xelem, val_w, val_b, nullptr, 0, Bp, 256, flag);

        // 5. deformable sampling + attention sum -> A (HWC; t_off dead)
        deform_sample_hwc<<<nDef, 256, 0, stream>>>(Bp, offset, attnb, A);

        // 6. final projection + bias + residual -> d_out (fp32 CHW)
        conv1x1_tiled<2, false, 0, true><<<gB, 256, 0, stream>>>(
            A, 0, out_w, out_b, x, xelem, outp, 256, flag);
    }
}